// Round 3
// baseline (12990.199 us; speedup 1.0000x reference)
//
#include <hip/hip_runtime.h>
#include <hip/hip_bf16.h>

typedef unsigned short u16;

// Problem constants
#define B_      256
#define SIG_    64
#define L_      1024
#define LAT_    256
#define RHSH_   512
#define T_      200

// ---------------- dtype-flex input loading ----------------
__device__ __forceinline__ bool probe_bf16(const void* tptr) {
    return ((const unsigned*)tptr)[0] != 0u;
}
__device__ __forceinline__ float ld_flex(const void* p, size_t i, bool bf) {
    return bf ? __bfloat162float(((const __hip_bfloat16*)p)[i]) : ((const float*)p)[i];
}
__device__ __forceinline__ u16 f2bf(float f) {
    unsigned x = __float_as_uint(f);
    unsigned r = x + 0x7FFFu + ((x >> 16) & 1u);   // RNE; finite values
    return (u16)(r >> 16);
}
__device__ __forceinline__ float bf2f(u16 v) {
    return __uint_as_float((unsigned)v << 16);
}

// ---------------- f16 dot2 helpers ----------------
typedef _Float16 half2_t __attribute__((ext_vector_type(2)));

#if defined(__has_builtin)
#if __has_builtin(__builtin_amdgcn_fdot2)
#define HAVE_FDOT2 1
#endif
#endif

__device__ __forceinline__ float fdot2(unsigned w, unsigned x, float c) {
#ifdef HAVE_FDOT2
    return __builtin_amdgcn_fdot2(__builtin_bit_cast(half2_t, w),
                                  __builtin_bit_cast(half2_t, x), c, false);
#else
    half2_t a = __builtin_bit_cast(half2_t, w);
    half2_t b = __builtin_bit_cast(half2_t, x);
    return c + (float)a.x * (float)b.x + (float)a.y * (float)b.y;
#endif
}
__device__ __forceinline__ unsigned pk16(float a, float b) {
    return __builtin_bit_cast(unsigned, __builtin_amdgcn_cvt_pkrtz(a, b));
}
__device__ __forceinline__ float fast_tanh(float x) {
    float e = __expf(2.0f * x);
    return 1.0f - 2.0f / (e + 1.0f);
}

// ---------------- workspace layout ----------------
// fp32 region (float element offsets)
static constexpr size_t Z0F  = 0;                                  // 256*256
static constexpr size_t EW0T = Z0F  + 65536;                       // 192x256
static constexpr size_t RW0T = EW0T + 49152;                       // 64x256
static constexpr size_t EW1T = RW0T + 16384;                       // 768x256
static constexpr size_t RW1T = EW1T + 196608;                      // 256x256
static constexpr size_t EW2T = RW1T + 65536;                       // 768x256
static constexpr size_t RW2T = EW2T + 196608;                      // 256x256
static constexpr size_t CB0  = RW2T + 65536;                       // 256
static constexpr size_t CB1  = CB0 + 256;
static constexpr size_t CB2  = CB1 + 256;
static constexpr size_t TFO  = CB2 + 256;                          // 200
static constexpr size_t FB0  = TFO + 256;                          // 512
static constexpr size_t FB1  = FB0 + 512;
static constexpr size_t FB2  = FB1 + 512;                          // 256
static constexpr size_t DB0  = FB2 + 256;                          // 512
static constexpr size_t DB1  = DB0 + 512;
static constexpr size_t DB2  = DB1 + 512;                          // 64
static constexpr size_t SALT = DB2 + 64;                           // 1 u32 (16 reserved)
static constexpr size_t FP32_END = SALT + 16;                      // 16B-aligned byte offset

// u16 region (ushort element offsets, rel. to FP32_END*4 bytes)
// rhs weights: f16 k-paired N-split [2][K/2][NH][2]; decoder: bf16 [K][N]; zs: [200][256][256]
static constexpr size_t FW0NS = 0;                 // 2*256*256
static constexpr size_t FW1NS = FW0NS + 131072;    // 2*512*256
static constexpr size_t FW2NS = FW1NS + 262144;    // 2*512*128
static constexpr size_t DW0B  = FW2NS + 131072;    // 256*512
static constexpr size_t DW1B  = DW0B + 131072;     // 512*512
static constexpr size_t DW2B  = DW1B + 262144;     // 512*64
static constexpr size_t ZS    = DW2B + 32768;      // 200*256*256 bf16
static constexpr size_t US_END = ZS + 13107200;

// pair-exchange region: 128 pairs x 2 dirs x 2 parity x 512 u64
static constexpr size_t EXCH_U64_PER_PAIR = 2048;
static constexpr size_t EXCH_OFF  = FP32_END * 4 + US_END * 2;     // 8-aligned
static constexpr size_t EXCH_BYTES = 128 * EXCH_U64_PER_PAIR * 8;
static constexpr size_t NEED_BYTES = EXCH_OFF + EXCH_BYTES;

// ---------------- prep kernels (dtype-flex) ----------------
__global__ void k_transpose(const void* __restrict__ in, float* __restrict__ out,
                            int N, int K, const void* __restrict__ tp) {
    bool bf = probe_bf16(tp);
    int idx = blockIdx.x * 256 + threadIdx.x;
    if (idx < N * K) {
        int k = idx / N;
        int n = idx - k * N;
        out[idx] = ld_flex(in, (size_t)n * K + k, bf);
    }
}

// W[N][K] row-major -> f16 k-paired N-split: u16 layout [2][K/2][NH][2]
__global__ void k_prep_wns16(const void* __restrict__ in, u16* __restrict__ out,
                             int N, int K, const void* __restrict__ tp) {
    bool bf = probe_bf16(tp);
    int idx = blockIdx.x * 256 + threadIdx.x;
    if (idx >= N * K) return;
    int NH = N >> 1;
    int kp = idx & 1;
    int c  = (idx >> 1) % NH;
    int r  = (idx >> 1) / NH;          // r = h*(K/2) + k2
    int k2 = r % (K >> 1);
    int h  = r / (K >> 1);
    int k  = 2 * k2 + kp;
    float v = ld_flex(in, (size_t)(h * NH + c) * K + k, bf);
    _Float16 hv = (_Float16)v;
    out[idx] = *(u16*)&hv;
}

// W[N][K] row-major -> bf16 [K][N]
__global__ void k_prep_wtb(const void* __restrict__ in, u16* __restrict__ out,
                           int N, int K, const void* __restrict__ tp) {
    bool bf = probe_bf16(tp);
    int idx = blockIdx.x * 256 + threadIdx.x;
    if (idx >= N * K) return;
    int n = idx % N;
    int k = idx / N;
    out[idx] = f2bf(ld_flex(in, (size_t)n * K + k, bf));
}

__global__ void k_cvt(const void* __restrict__ in, float* __restrict__ out, int n,
                      const void* __restrict__ tp) {
    bool bf = probe_bf16(tp);
    int i = blockIdx.x * 256 + threadIdx.x;
    if (i < n) out[i] = ld_flex(in, i, bf);
}

__global__ void k_cvt_add(const void* __restrict__ a, const void* __restrict__ b,
                          float* __restrict__ out, int n, const void* __restrict__ tp) {
    bool bf = probe_bf16(tp);
    int i = blockIdx.x * 256 + threadIdx.x;
    if (i < n) out[i] = ld_flex(a, i, bf) + ld_flex(b, i, bf);
}

__global__ void k_fill(float* __restrict__ out, int n, float v) {
    int i = blockIdx.x * 256 + threadIdx.x;
    if (i < n) out[i] = v;
}

__global__ void k_bump(unsigned* p) {
    if (threadIdx.x == 0) p[0] = p[0] + 1u;
}

// ---------------- encoder: z0 = enc(y)[:, :, 0] (only y[:, :, 0:4] matters) ----------------
__global__ __launch_bounds__(256) void k_encoder(
    const void* __restrict__ y, const void* __restrict__ tp,
    const float* __restrict__ ew0T, const float* __restrict__ rw0T, const float* __restrict__ cb0,
    const float* __restrict__ ew1T, const float* __restrict__ rw1T, const float* __restrict__ cb1,
    const float* __restrict__ ew2T, const float* __restrict__ rw2T, const float* __restrict__ cb2,
    float* __restrict__ z0f) {
    bool bf = probe_bf16(tp);
    int b = blockIdx.x;
    int o = threadIdx.x;
    __shared__ float ys[64][4];
    __shared__ float x1[3][256];
    __shared__ float x2[2][256];

    {
        int i = o >> 2, l = o & 3;
        ys[i][l] = ld_flex(y, (size_t)b * SIG_ * L_ + (size_t)i * L_ + l, bf);
    }
    __syncthreads();

    {
        float a0 = 0.f, a1 = 0.f, a2 = 0.f;
        for (int i = 0; i < 64; i++) {
            float w0 = ew0T[(i * 3 + 0) * 256 + o];
            float w1 = ew0T[(i * 3 + 1) * 256 + o];
            float w2 = ew0T[(i * 3 + 2) * 256 + o];
            float rw = rw0T[i * 256 + o];
            float v0 = ys[i][0], v1 = ys[i][1], v2 = ys[i][2], v3 = ys[i][3];
            a0 += w1 * v0 + w2 * v1 + rw * v0;
            a1 += w0 * v0 + w1 * v1 + w2 * v2 + rw * v1;
            a2 += w0 * v1 + w1 * v2 + w2 * v3 + rw * v2;
        }
        float cb = cb0[o];
        x1[0][o] = tanhf(a0 + cb);
        x1[1][o] = tanhf(a1 + cb);
        x1[2][o] = tanhf(a2 + cb);
    }
    __syncthreads();

    {
        float a0 = 0.f, a1 = 0.f;
        for (int i = 0; i < 256; i++) {
            float w0 = ew1T[(i * 3 + 0) * 256 + o];
            float w1 = ew1T[(i * 3 + 1) * 256 + o];
            float w2 = ew1T[(i * 3 + 2) * 256 + o];
            float rw = rw1T[i * 256 + o];
            float v0 = x1[0][i], v1 = x1[1][i], v2 = x1[2][i];
            a0 += w1 * v0 + w2 * v1 + rw * v0;
            a1 += w0 * v0 + w1 * v1 + w2 * v2 + rw * v1;
        }
        float cb = cb1[o];
        x2[0][o] = tanhf(a0 + cb);
        x2[1][o] = tanhf(a1 + cb);
    }
    __syncthreads();

    {
        float a0 = 0.f;
        for (int i = 0; i < 256; i++) {
            float w1 = ew2T[(i * 3 + 1) * 256 + o];
            float w2 = ew2T[(i * 3 + 2) * 256 + o];
            float rw = rw2T[i * 256 + o];
            a0 += w1 * x2[0][i] + w2 * x2[1][i] + rw * x2[0][i];
        }
        z0f[(size_t)b * 256 + o] = a0 + cb2[o];
    }
}

// ---------------- N-split fused layer (f16 dot2) with RK-fused receive/tail ----------------
// Protocol identical to the verified R1 kernel: pair blocks (p, p+128), tagged u64
// relaxed agent-scope exchange, wave-exclusive recv of exactly the remote k-slice
// that wave reads. New: f16 k-paired weights consumed via v_dot2_f32_f16; h1/h2
// carried as packed f16x2 in LDS; z inputs packed inline via cvt_pkrtz; remote-half
// weights register-prefetched BEFORE local compute so post-recv work is LDS+VALU only.
#define RM_NONE 0
#define RM_PLAIN 1
#define RM_S1 2
#define RM_S2 3
#define RM_S34 4
#define TL_PLAIN 0
#define TL_RK 1
#define TL_K4 2

template <int KIN, int NOUT, bool ACT, int RM, int TL>
__device__ __forceinline__ void layer_ns(
    float* zin,                                     // RM!=PLAIN: f32 [2][KIN] input (z-space)
    unsigned* xpin,                                 // RM==PLAIN: packed f16x2 [2][KIN/2]
    const u16* __restrict__ wbu16,                  // f16 k-paired [K/2][NH][2], my half
    const float* __restrict__ bias,                 // my half (pre-offset)
    unsigned* xpo,                                  // TL_PLAIN: packed out [2][NOUT/2]
    float* scratch,                                 // LDS 4096 floats
    unsigned long long* __restrict__ sendBuf,
    const unsigned long long* __restrict__ recvBuf,
    unsigned sendTag, unsigned recvTag, int nHalf, int tid,
    float* zbL, float* acL, float* ztL,             // LDS [2][256] RK state
    float rcAC, float rcZT,                         // receive-transform coefs
    bool tInit, float tcAC, float tcZT,             // tail coefs
    u16* zsOut) {
    constexpr int NH  = NOUT / 2;
    constexpr int CQ  = NH / 4;        // threads per phase (4 cols each)
    constexpr int NPH = 512 / CQ;      // phases over K
    constexpr int KH  = KIN / 2;
    constexpr int KC2 = KH / NPH;      // k per thread per half
    constexpr int K2C = KC2 / 2;       // k-pairs per thread per half
    constexpr int WK  = KH / 8;        // k per wave per half (== wave's compute slice)
    constexpr bool ZIN = (RM != RM_PLAIN);
    const int cq = tid & (CQ - 1);
    const int ph = tid / CQ;
    const int locB  = nHalf * KH;
    const int remB  = KH - locB;
    const int locB2 = locB >> 1;
    const int remB2 = remB >> 1;
    const unsigned* wb32 = (const unsigned*)wbu16;

    // prefetch remote-half weights into registers (completes under local compute + poll)
    uint4 wr4[K2C];
    {
        const unsigned* wr = wb32 + ((size_t)(remB2 + ph * K2C)) * NH + 4 * cq;
#pragma unroll
        for (int j = 0; j < K2C; j++) wr4[j] = *(const uint4*)(wr + (size_t)j * NH);
    }

    float4 a0 = {0.f, 0.f, 0.f, 0.f}, a1 = {0.f, 0.f, 0.f, 0.f};
    {
        const unsigned* wl = wb32 + ((size_t)(locB2 + ph * K2C)) * NH + 4 * cq;
        if constexpr (ZIN) {
            const float* zl0 = zin + locB + ph * KC2;
            const float* zl1 = zin + KIN + locB + ph * KC2;
#pragma unroll
            for (int j = 0; j < K2C; j++) {
                uint4 w4 = *(const uint4*)(wl + (size_t)j * NH);
                float2 p0 = *(const float2*)(zl0 + 2 * j);
                float2 p1 = *(const float2*)(zl1 + 2 * j);
                unsigned x0 = pk16(p0.x, p0.y), x1 = pk16(p1.x, p1.y);
                a0.x = fdot2(w4.x, x0, a0.x); a0.y = fdot2(w4.y, x0, a0.y);
                a0.z = fdot2(w4.z, x0, a0.z); a0.w = fdot2(w4.w, x0, a0.w);
                a1.x = fdot2(w4.x, x1, a1.x); a1.y = fdot2(w4.y, x1, a1.y);
                a1.z = fdot2(w4.z, x1, a1.z); a1.w = fdot2(w4.w, x1, a1.w);
            }
        } else {
            const unsigned* xq0 = xpin + locB2 + ph * K2C;
            const unsigned* xq1 = xpin + KIN / 2 + locB2 + ph * K2C;
#pragma unroll
            for (int j = 0; j < K2C; j++) {
                uint4 w4 = *(const uint4*)(wl + (size_t)j * NH);
                unsigned x0 = xq0[j], x1 = xq1[j];
                a0.x = fdot2(w4.x, x0, a0.x); a0.y = fdot2(w4.y, x0, a0.y);
                a0.z = fdot2(w4.z, x0, a0.z); a0.w = fdot2(w4.w, x0, a0.w);
                a1.x = fdot2(w4.x, x1, a1.x); a1.y = fdot2(w4.y, x1, a1.y);
                a1.z = fdot2(w4.z, x1, a1.z); a1.w = fdot2(w4.w, x1, a1.w);
            }
        }
    }

    if constexpr (RM != RM_NONE) {
        const int lane = tid & 63;
        const int wave = tid >> 6;
        if constexpr (RM == RM_PLAIN) {
            // KIN=512: full wave active; even lanes pack f16x2 pairs
            const int r = lane / WK;
            const int kRel = wave * WK + (lane % WK);
            unsigned long long p;
            for (;;) {
                p = __hip_atomic_load(&recvBuf[r * KH + kRel],
                                      __ATOMIC_RELAXED, __HIP_MEMORY_SCOPE_AGENT);
                if ((unsigned)(p >> 32) == recvTag) break;
                __builtin_amdgcn_s_sleep(2);
            }
            float kv = __uint_as_float((unsigned)p);
            float kn = __shfl_down(kv, 1);
            if ((lane & 1) == 0)
                xpin[r * (KIN / 2) + ((remB + kRel) >> 1)] = pk16(kv, kn);
        } else {
            if (lane < 2 * WK) {
                const int r = lane / WK;
                const int kRel = wave * WK + (lane % WK);
                unsigned long long p;
                for (;;) {
                    p = __hip_atomic_load(&recvBuf[r * KH + kRel],
                                          __ATOMIC_RELAXED, __HIP_MEMORY_SCOPE_AGENT);
                    if ((unsigned)(p >> 32) == recvTag) break;
                    __builtin_amdgcn_s_sleep(2);
                }
                float kv = __uint_as_float((unsigned)p);
                const int xi = r * KIN + remB + kRel;
                if constexpr (RM == RM_S1) {
                    // zin == zb; k4 of prev step
                    zin[xi] = acL[xi] + rcAC * kv;
                } else if constexpr (RM == RM_S2) {
                    float zv = zbL[xi];
                    acL[xi] = zv + rcAC * kv;
                    zin[xi] = zv + rcZT * kv;
                } else {  // RM_S34
                    float zv = zbL[xi];
                    acL[xi] += rcAC * kv;
                    zin[xi] = zv + rcZT * kv;
                }
            }
        }
    }

    // remote half from prefetched registers
    if constexpr (ZIN) {
        const float* zr0 = zin + remB + ph * KC2;
        const float* zr1 = zin + KIN + remB + ph * KC2;
#pragma unroll
        for (int j = 0; j < K2C; j++) {
            float2 p0 = *(const float2*)(zr0 + 2 * j);
            float2 p1 = *(const float2*)(zr1 + 2 * j);
            unsigned x0 = pk16(p0.x, p0.y), x1 = pk16(p1.x, p1.y);
            a0.x = fdot2(wr4[j].x, x0, a0.x); a0.y = fdot2(wr4[j].y, x0, a0.y);
            a0.z = fdot2(wr4[j].z, x0, a0.z); a0.w = fdot2(wr4[j].w, x0, a0.w);
            a1.x = fdot2(wr4[j].x, x1, a1.x); a1.y = fdot2(wr4[j].y, x1, a1.y);
            a1.z = fdot2(wr4[j].z, x1, a1.z); a1.w = fdot2(wr4[j].w, x1, a1.w);
        }
    } else {
        const unsigned* xq0 = xpin + remB2 + ph * K2C;
        const unsigned* xq1 = xpin + KIN / 2 + remB2 + ph * K2C;
#pragma unroll
        for (int j = 0; j < K2C; j++) {
            unsigned x0 = xq0[j], x1 = xq1[j];
            a0.x = fdot2(wr4[j].x, x0, a0.x); a0.y = fdot2(wr4[j].y, x0, a0.y);
            a0.z = fdot2(wr4[j].z, x0, a0.z); a0.w = fdot2(wr4[j].w, x0, a0.w);
            a1.x = fdot2(wr4[j].x, x1, a1.x); a1.y = fdot2(wr4[j].y, x1, a1.y);
            a1.z = fdot2(wr4[j].z, x1, a1.z); a1.w = fdot2(wr4[j].w, x1, a1.w);
        }
    }

    *(float4*)(scratch + (size_t)(ph * 2 + 0) * NH + 4 * cq) = a0;
    *(float4*)(scratch + (size_t)(ph * 2 + 1) * NH + 4 * cq) = a1;
    __syncthreads();
    if (tid < 2 * NH) {
        const int r = tid / NH, c = tid % NH;
        float s = 0.f;
#pragma unroll
        for (int p = 0; p < NPH; p++) s += scratch[(size_t)(p * 2 + r) * NH + c];
        s += bias[c];
        if (ACT) s = fast_tanh(s);
        {
            unsigned long long packed =
                ((unsigned long long)sendTag << 32) | (unsigned long long)__float_as_uint(s);
            __hip_atomic_store(&sendBuf[r * NH + c], packed,
                               __ATOMIC_RELAXED, __HIP_MEMORY_SCOPE_AGENT);
        }
        if constexpr (TL == TL_PLAIN) {
            float sn = __shfl_down(s, 1);
            if ((tid & 1) == 0)
                xpo[r * (NOUT / 2) + ((nHalf * NH + c) >> 1)] = pk16(s, sn);
        } else if constexpr (TL == TL_RK) {
            const int zi = r * 256 + nHalf * NH + c;
            float zv = zbL[zi];
            acL[zi] = (tInit ? zv : acL[zi]) + tcAC * s;
            ztL[zi] = zv + tcZT * s;
        } else {  // TL_K4
            const int zi = r * 256 + nHalf * NH + c;
            float zn = acL[zi] + tcAC * s;
            zbL[zi] = zn;
            zsOut[zi] = f2bf(zn);
        }
    }
    __syncthreads();
}

// ---------------- N-split fused ODE: 256 blocks x 512 threads ----------------
__global__ __launch_bounds__(512) void k_ode_ns(
    const u16* __restrict__ fw0ns, const float* __restrict__ fb0,
    const u16* __restrict__ fw1ns, const float* __restrict__ fb1,
    const u16* __restrict__ fw2ns, const float* __restrict__ fb2,
    const float* __restrict__ tf, const float* __restrict__ z0f,
    const unsigned* __restrict__ saltp,
    u16* __restrict__ zs, unsigned long long* __restrict__ ex) {
    __shared__ __align__(16) float zb[512];       // [2][256] full z, replicated on both blocks
    __shared__ __align__(16) float zt[512];
    __shared__ __align__(16) float ac[512];
    __shared__ __align__(16) unsigned h1p[512];   // [2][256] packed f16x2
    __shared__ __align__(16) unsigned h2p[512];
    __shared__ __align__(16) float scratch[4096];

    const int tid = threadIdx.x;
    const int pairId = blockIdx.x & 127;
    const int nHalf  = blockIdx.x >> 7;
    const int row0 = pairId * 2;
    unsigned long long* exBase = ex + (size_t)pairId * EXCH_U64_PER_PAIR;

    const unsigned salt = __hip_atomic_load(saltp, __ATOMIC_RELAXED, __HIP_MEMORY_SCOPE_AGENT);
    unsigned tag = salt << 13;                    // 12 tags/step * 199 = 2388 < 8192

#define SB(t) (exBase + ((size_t)(nHalf * 2 + ((t) & 1)) * 512))
#define RB(t) ((const unsigned long long*)(exBase + ((size_t)((1 - nHalf) * 2 + ((t) & 1)) * 512)))

    const u16* fw0w = fw0ns + (size_t)nHalf * 65536;    // per-half: 128*256 u32
    const u16* fw1w = fw1ns + (size_t)nHalf * 131072;   // per-half: 256*256 u32
    const u16* fw2w = fw2ns + (size_t)nHalf * 65536;    // per-half: 256*128 u32
    const float* fb0o = fb0 + nHalf * 256;
    const float* fb1o = fb1 + nHalf * 256;
    const float* fb2o = fb2 + nHalf * 128;

    zb[tid] = z0f[(size_t)(row0 + (tid >> 8)) * 256 + (tid & 255)];
    __syncthreads();

    // store z0 (my local half) as bf16
    if (tid < 256) {
        int r = tid >> 7, c = tid & 127;
        zs[(size_t)(row0 + r) * 256 + nHalf * 128 + c] = f2bf(zb[r * 256 + nHalf * 128 + c]);
    }

    float h6prev = 0.f;
    unsigned tcPrev = 0;

    for (int t = 0; t < T_ - 1; t++) {
        float hstep = tf[t + 1] - tf[t];
        float hh = 0.5f * hstep;
        float h3 = hstep * (1.0f / 3.0f);
        float h6 = hstep * (1.0f / 6.0f);

        unsigned ta, tb, tc;
        // ---- stage 1: input zb; tail produces k1
        ta = ++tag; tb = ++tag; tc = ++tag;
        if (t == 0)
            layer_ns<256, 512, true, RM_NONE, TL_PLAIN>(zb, nullptr, fw0w, fb0o, h1p, scratch,
                SB(ta), nullptr, ta, 0u, nHalf, tid, zb, ac, zt, 0.f, 0.f, false, 0.f, 0.f, nullptr);
        else
            layer_ns<256, 512, true, RM_S1, TL_PLAIN>(zb, nullptr, fw0w, fb0o, h1p, scratch,
                SB(ta), RB(tcPrev), ta, tcPrev, nHalf, tid, zb, ac, zt, h6prev, 0.f, false, 0.f, 0.f, nullptr);
        layer_ns<512, 512, true, RM_PLAIN, TL_PLAIN>(nullptr, h1p, fw1w, fb1o, h2p, scratch,
            SB(tb), RB(ta), tb, ta, nHalf, tid, zb, ac, zt, 0.f, 0.f, false, 0.f, 0.f, nullptr);
        layer_ns<512, 256, false, RM_PLAIN, TL_RK>(nullptr, h2p, fw2w, fb2o, nullptr, scratch,
            SB(tc), RB(tb), tc, tb, nHalf, tid, zb, ac, zt, 0.f, 0.f, true, h6, hh, nullptr);
        tcPrev = tc;

        // ---- stage 2: input zt; recv k1; tail produces k2
        ta = ++tag; tb = ++tag; tc = ++tag;
        layer_ns<256, 512, true, RM_S2, TL_PLAIN>(zt, nullptr, fw0w, fb0o, h1p, scratch,
            SB(ta), RB(tcPrev), ta, tcPrev, nHalf, tid, zb, ac, zt, h6, hh, false, 0.f, 0.f, nullptr);
        layer_ns<512, 512, true, RM_PLAIN, TL_PLAIN>(nullptr, h1p, fw1w, fb1o, h2p, scratch,
            SB(tb), RB(ta), tb, ta, nHalf, tid, zb, ac, zt, 0.f, 0.f, false, 0.f, 0.f, nullptr);
        layer_ns<512, 256, false, RM_PLAIN, TL_RK>(nullptr, h2p, fw2w, fb2o, nullptr, scratch,
            SB(tc), RB(tb), tc, tb, nHalf, tid, zb, ac, zt, 0.f, 0.f, false, h3, hh, nullptr);
        tcPrev = tc;

        // ---- stage 3: input zt; recv k2; tail produces k3
        ta = ++tag; tb = ++tag; tc = ++tag;
        layer_ns<256, 512, true, RM_S34, TL_PLAIN>(zt, nullptr, fw0w, fb0o, h1p, scratch,
            SB(ta), RB(tcPrev), ta, tcPrev, nHalf, tid, zb, ac, zt, h3, hh, false, 0.f, 0.f, nullptr);
        layer_ns<512, 512, true, RM_PLAIN, TL_PLAIN>(nullptr, h1p, fw1w, fb1o, h2p, scratch,
            SB(tb), RB(ta), tb, ta, nHalf, tid, zb, ac, zt, 0.f, 0.f, false, 0.f, 0.f, nullptr);
        layer_ns<512, 256, false, RM_PLAIN, TL_RK>(nullptr, h2p, fw2w, fb2o, nullptr, scratch,
            SB(tc), RB(tb), tc, tb, nHalf, tid, zb, ac, zt, 0.f, 0.f, false, h3, hstep, nullptr);
        tcPrev = tc;

        // ---- stage 4: input zt; recv k3; tail produces k4 and z_{t+1} (+ bf16 store)
        ta = ++tag; tb = ++tag; tc = ++tag;
        layer_ns<256, 512, true, RM_S34, TL_PLAIN>(zt, nullptr, fw0w, fb0o, h1p, scratch,
            SB(ta), RB(tcPrev), ta, tcPrev, nHalf, tid, zb, ac, zt, h3, hstep, false, 0.f, 0.f, nullptr);
        layer_ns<512, 512, true, RM_PLAIN, TL_PLAIN>(nullptr, h1p, fw1w, fb1o, h2p, scratch,
            SB(tb), RB(ta), tb, ta, nHalf, tid, zb, ac, zt, 0.f, 0.f, false, 0.f, 0.f, nullptr);
        layer_ns<512, 256, false, RM_PLAIN, TL_K4>(nullptr, h2p, fw2w, fb2o, nullptr, scratch,
            SB(tc), RB(tb), tc, tb, nHalf, tid, zb, ac, zt, 0.f, 0.f, false, h6, 0.f,
            zs + (size_t)(t + 1) * 65536 + (size_t)row0 * 256);
        tcPrev = tc;
        h6prev = h6;
    }
#undef SB
#undef RB
}

// ---------------- batched decode pass: zs[200*256] rows -> out ----------------
// grid 2560 = 256 b x 10 t-chunks of 20; block 512 threads
template <int K>
__device__ __forceinline__ void dec_layer512(
    const float* xin, const u16* __restrict__ wt, const float* __restrict__ bias,
    float* xout, int tid) {
    const int q = tid & 127;          // col quad (4 cols)
    const int g = tid >> 7;           // row group (5 rows)
    const u16* wp = wt + 4 * q;
    const float* xr = xin + (size_t)g * 5 * K;
    float4 a[5];
#pragma unroll
    for (int r = 0; r < 5; r++) a[r] = {0.f, 0.f, 0.f, 0.f};
#pragma unroll 4
    for (int k = 0; k < K; k++) {
        uint2 w = *(const uint2*)(wp + (size_t)k * 512);
        float w0 = __uint_as_float(w.x << 16);
        float w1 = __uint_as_float(w.x & 0xFFFF0000u);
        float w2 = __uint_as_float(w.y << 16);
        float w3 = __uint_as_float(w.y & 0xFFFF0000u);
#pragma unroll
        for (int r = 0; r < 5; r++) {
            float v = xr[r * K + k];
            a[r].x += v * w0; a[r].y += v * w1; a[r].z += v * w2; a[r].w += v * w3;
        }
    }
    float b0 = bias[4 * q + 0], b1 = bias[4 * q + 1], b2 = bias[4 * q + 2], b3 = bias[4 * q + 3];
#pragma unroll
    for (int r = 0; r < 5; r++) {
        float4 o;
        o.x = fast_tanh(a[r].x + b0);
        o.y = fast_tanh(a[r].y + b1);
        o.z = fast_tanh(a[r].z + b2);
        o.w = fast_tanh(a[r].w + b3);
        *(float4*)(xout + (size_t)(g * 5 + r) * 512 + 4 * q) = o;
    }
}

__global__ __launch_bounds__(512) void k_decode(
    const u16* __restrict__ zs,
    const u16* __restrict__ dw0b, const float* __restrict__ db0,
    const u16* __restrict__ dw1b, const float* __restrict__ db1,
    const u16* __restrict__ dw2b, const float* __restrict__ db2,
    float* __restrict__ out) {
    __shared__ __align__(16) float xb[20 * 256];    // 20 KB
    __shared__ __align__(16) float hh1[20 * 512];   // 40 KB
    __shared__ __align__(16) float hh2[20 * 512];   // 40 KB
    const int tid = threadIdx.x;
    const int b  = blockIdx.x & 255;
    const int t0 = (blockIdx.x >> 8) * 20;

    for (int i = tid; i < 20 * 256; i += 512) {
        int r = i >> 8, k = i & 255;
        xb[i] = bf2f(zs[(size_t)(t0 + r) * 65536 + (size_t)b * 256 + k]);
    }
    __syncthreads();

    dec_layer512<256>(xb, dw0b, db0, hh1, tid);
    __syncthreads();
    dec_layer512<512>(hh1, dw1b, db1, hh2, tid);
    __syncthreads();

    if (tid < 320) {
        const int q = tid & 15;       // 4 cols of 64
        const int r = tid >> 4;       // row (timestep) in [0,20)
        const u16* wp = dw2b + 4 * q;
        const float* xr = hh2 + (size_t)r * 512;
        float4 a = {0.f, 0.f, 0.f, 0.f};
#pragma unroll 4
        for (int k = 0; k < 512; k++) {
            uint2 w = *(const uint2*)(wp + (size_t)k * 64);
            float w0 = __uint_as_float(w.x << 16);
            float w1 = __uint_as_float(w.x & 0xFFFF0000u);
            float w2 = __uint_as_float(w.y << 16);
            float w3 = __uint_as_float(w.y & 0xFFFF0000u);
            float v = xr[k];
            a.x += v * w0; a.y += v * w1; a.z += v * w2; a.w += v * w3;
        }
        const int tt = t0 + r;
        out[((size_t)b * 64 + 4 * q + 0) * 200 + tt] = a.x + db2[4 * q + 0];
        out[((size_t)b * 64 + 4 * q + 1) * 200 + tt] = a.y + db2[4 * q + 1];
        out[((size_t)b * 64 + 4 * q + 2) * 200 + tt] = a.z + db2[4 * q + 2];
        out[((size_t)b * 64 + 4 * q + 3) * 200 + tt] = a.w + db2[4 * q + 3];
    }
}

// ---------------- host launch ----------------
#define GRID256(n) ((((n) + 255) / 256))

static const int DICT_SIZES[26] = {
    16777216, 200, 49152, 256, 16384, 256, 196608, 256, 65536, 256,
    196608, 256, 65536, 256, 131072, 512, 262144, 512, 131072, 256,
    131072, 512, 262144, 512, 32768, 64};
static const int ALPHA_SIZES[26] = {
    512, 512, 64, 131072, 262144, 32768, 256, 256, 256, 49152,
    196608, 196608, 512, 512, 256, 131072, 262144, 131072, 256, 256,
    256, 16384, 65536, 65536, 200, 16777216};
static const int ALPHA_MAP[26] = {
    25, 24, 9, 6, 21, 18, 10, 7, 22, 19, 11, 8, 23, 20, 15, 12, 16, 13, 17, 14,
    3, 0, 4, 1, 5, 2};

extern "C" void kernel_launch(void* const* d_in, const int* in_sizes, int n_in,
                              void* d_out, int out_size, void* d_ws, size_t ws_size,
                              hipStream_t stream) {
    float* out = (float*)d_out;   // reference output dtype is FLOAT32

    bool dict_ok = (n_in == 26), alpha_ok = (n_in == 26);
    for (int i = 0; i < 26 && i < n_in; i++) {
        if (in_sizes[i] != DICT_SIZES[i]) dict_ok = false;
        if (in_sizes[i] != ALPHA_SIZES[i]) alpha_ok = false;
    }
    const void* in[26];
    if (dict_ok) {
        for (int s = 0; s < 26; s++) in[s] = d_in[s];
    } else if (alpha_ok) {
        for (int s = 0; s < 26; s++) in[s] = d_in[ALPHA_MAP[s]];
    } else {
        k_fill<<<GRID256(out_size), 256, 0, stream>>>(out, out_size, 1000.0f);
        return;
    }
    if (ws_size < NEED_BYTES) {
        k_fill<<<GRID256(out_size), 256, 0, stream>>>(out, out_size, 500.0f);
        return;
    }

    const void* y   = in[0];
    const void* t   = in[1];
    const void* ew0 = in[2];
    const void* eb0 = in[3];
    const void* rw0 = in[4];
    const void* rb0 = in[5];
    const void* ew1 = in[6];
    const void* eb1 = in[7];
    const void* rw1 = in[8];
    const void* rb1 = in[9];
    const void* ew2 = in[10];
    const void* eb2 = in[11];
    const void* rw2 = in[12];
    const void* rb2 = in[13];
    const void* fw0 = in[14];
    const void* fb0 = in[15];
    const void* fw1 = in[16];
    const void* fb1 = in[17];
    const void* fw2 = in[18];
    const void* fb2 = in[19];
    const void* dw0 = in[20];
    const void* db0 = in[21];
    const void* dw1 = in[22];
    const void* db1 = in[23];
    const void* dw2 = in[24];
    const void* db2 = in[25];

    float* ws = (float*)d_ws;
    u16* wns = (u16*)(ws + FP32_END);
    unsigned long long* ex = (unsigned long long*)((char*)d_ws + EXCH_OFF);

    k_bump<<<1, 1, 0, stream>>>((unsigned*)(ws + SALT));

    // encoder weights stay fp32 (one-shot kernel, not on the hot path)
    k_transpose<<<GRID256(256 * 192), 256, 0, stream>>>(ew0, ws + EW0T, 256, 192, t);
    k_transpose<<<GRID256(256 * 64),  256, 0, stream>>>(rw0, ws + RW0T, 256, 64, t);
    k_transpose<<<GRID256(256 * 768), 256, 0, stream>>>(ew1, ws + EW1T, 256, 768, t);
    k_transpose<<<GRID256(256 * 256), 256, 0, stream>>>(rw1, ws + RW1T, 256, 256, t);
    k_transpose<<<GRID256(256 * 768), 256, 0, stream>>>(ew2, ws + EW2T, 256, 768, t);
    k_transpose<<<GRID256(256 * 256), 256, 0, stream>>>(rw2, ws + RW2T, 256, 256, t);

    // rhs weights -> f16 k-paired N-split [2][K/2][NH][2]
    k_prep_wns16<<<GRID256(512 * 256), 256, 0, stream>>>(fw0, wns + FW0NS, 512, 256, t);
    k_prep_wns16<<<GRID256(512 * 512), 256, 0, stream>>>(fw1, wns + FW1NS, 512, 512, t);
    k_prep_wns16<<<GRID256(256 * 512), 256, 0, stream>>>(fw2, wns + FW2NS, 256, 512, t);
    // decoder weights -> bf16 plain-T [K][N]
    k_prep_wtb<<<GRID256(512 * 256), 256, 0, stream>>>(dw0, wns + DW0B, 512, 256, t);
    k_prep_wtb<<<GRID256(512 * 512), 256, 0, stream>>>(dw1, wns + DW1B, 512, 512, t);
    k_prep_wtb<<<GRID256(64 * 512),  256, 0, stream>>>(dw2, wns + DW2B, 64, 512, t);

    k_cvt<<<GRID256(512), 256, 0, stream>>>(fb0, ws + FB0, 512, t);
    k_cvt<<<GRID256(512), 256, 0, stream>>>(fb1, ws + FB1, 512, t);
    k_cvt<<<GRID256(256), 256, 0, stream>>>(fb2, ws + FB2, 256, t);
    k_cvt<<<GRID256(512), 256, 0, stream>>>(db0, ws + DB0, 512, t);
    k_cvt<<<GRID256(512), 256, 0, stream>>>(db1, ws + DB1, 512, t);
    k_cvt<<<GRID256(64),  256, 0, stream>>>(db2, ws + DB2, 64, t);
    k_cvt<<<GRID256(200), 256, 0, stream>>>(t,   ws + TFO, 200, t);
    k_cvt_add<<<GRID256(256), 256, 0, stream>>>(eb0, rb0, ws + CB0, 256, t);
    k_cvt_add<<<GRID256(256), 256, 0, stream>>>(eb1, rb1, ws + CB1, 256, t);
    k_cvt_add<<<GRID256(256), 256, 0, stream>>>(eb2, rb2, ws + CB2, 256, t);

    k_encoder<<<B_, 256, 0, stream>>>(y, t,
        ws + EW0T, ws + RW0T, ws + CB0,
        ws + EW1T, ws + RW1T, ws + CB1,
        ws + EW2T, ws + RW2T, ws + CB2,
        ws + Z0F);

    k_ode_ns<<<256, 512, 0, stream>>>(
        wns + FW0NS, ws + FB0, wns + FW1NS, ws + FB1, wns + FW2NS, ws + FB2,
        ws + TFO, ws + Z0F, (const unsigned*)(ws + SALT),
        wns + ZS, ex);

    k_decode<<<2560, 512, 0, stream>>>(
        wns + ZS, wns + DW0B, ws + DB0, wns + DW1B, ws + DB1, wns + DW2B, ws + DB2, out);
}

// Round 5
// 7488.108 us; speedup vs baseline: 1.7348x; 1.7348x over previous
//
#include <hip/hip_runtime.h>
#include <hip/hip_bf16.h>

typedef unsigned short u16;

// Problem constants
#define B_      256
#define SIG_    64
#define L_      1024
#define LAT_    256
#define RHSH_   512
#define T_      200

// ---------------- dtype-flex input loading ----------------
__device__ __forceinline__ bool probe_bf16(const void* tptr) {
    return ((const unsigned*)tptr)[0] != 0u;
}
__device__ __forceinline__ float ld_flex(const void* p, size_t i, bool bf) {
    return bf ? __bfloat162float(((const __hip_bfloat16*)p)[i]) : ((const float*)p)[i];
}
__device__ __forceinline__ u16 f2bf(float f) {
    unsigned x = __float_as_uint(f);
    unsigned r = x + 0x7FFFu + ((x >> 16) & 1u);   // RNE; finite values
    return (u16)(r >> 16);
}
__device__ __forceinline__ float bf2f(u16 v) {
    return __uint_as_float((unsigned)v << 16);
}

// ---------------- f16 dot2 helpers ----------------
typedef _Float16 half2_t __attribute__((ext_vector_type(2)));

#if defined(__has_builtin)
#if __has_builtin(__builtin_amdgcn_fdot2)
#define HAVE_FDOT2 1
#endif
#endif

__device__ __forceinline__ float fdot2(unsigned w, unsigned x, float c) {
#ifdef HAVE_FDOT2
    return __builtin_amdgcn_fdot2(__builtin_bit_cast(half2_t, w),
                                  __builtin_bit_cast(half2_t, x), c, false);
#else
    half2_t a = __builtin_bit_cast(half2_t, w);
    half2_t b = __builtin_bit_cast(half2_t, x);
    return c + (float)a.x * (float)b.x + (float)a.y * (float)b.y;
#endif
}
__device__ __forceinline__ unsigned pk16(float a, float b) {
    return __builtin_bit_cast(unsigned, __builtin_amdgcn_cvt_pkrtz(a, b));
}
__device__ __forceinline__ float fast_tanh(float x) {
    float e = __expf(2.0f * x);
    return 1.0f - 2.0f / (e + 1.0f);
}

// ---------------- workspace layout ----------------
// fp32 region (float element offsets)
static constexpr size_t Z0F  = 0;                                  // 256*256
static constexpr size_t EW0T = Z0F  + 65536;                       // 192x256
static constexpr size_t RW0T = EW0T + 49152;                       // 64x256
static constexpr size_t EW1T = RW0T + 16384;                       // 768x256
static constexpr size_t RW1T = EW1T + 196608;                      // 256x256
static constexpr size_t EW2T = RW1T + 65536;                       // 768x256
static constexpr size_t RW2T = EW2T + 196608;                      // 256x256
static constexpr size_t CB0  = RW2T + 65536;                       // 256
static constexpr size_t CB1  = CB0 + 256;
static constexpr size_t CB2  = CB1 + 256;
static constexpr size_t TFO  = CB2 + 256;                          // 200
static constexpr size_t FB0  = TFO + 256;                          // 512
static constexpr size_t FB1  = FB0 + 512;
static constexpr size_t FB2  = FB1 + 512;                          // 256
static constexpr size_t DB0  = FB2 + 256;                          // 512
static constexpr size_t DB1  = DB0 + 512;
static constexpr size_t DB2  = DB1 + 512;                          // 64
static constexpr size_t FP32_END = DB2 + 64 + 16;                  // padded

// u16 region (ushort element offsets, rel. to FP32_END*4 bytes)
// rhs weights f16 k-paired full-N [K/2][N][2]; decoder bf16 [K][N]; zs [200][256][256]
static constexpr size_t FW0KP = 0;                 // 512*256
static constexpr size_t FW1KP = FW0KP + 131072;    // 512*512
static constexpr size_t FW2KP = FW1KP + 262144;    // 256*512
static constexpr size_t DW0B  = FW2KP + 131072;    // 256*512
static constexpr size_t DW1B  = DW0B + 131072;     // 512*512
static constexpr size_t DW2B  = DW1B + 262144;     // 512*64
static constexpr size_t ZS    = DW2B + 32768;      // 200*256*256 bf16
static constexpr size_t US_END = ZS + 13107200;

static constexpr size_t NEED_BYTES = FP32_END * 4 + US_END * 2;

// ---------------- prep kernels (dtype-flex) ----------------
__global__ void k_transpose(const void* __restrict__ in, float* __restrict__ out,
                            int N, int K, const void* __restrict__ tp) {
    bool bf = probe_bf16(tp);
    int idx = blockIdx.x * 256 + threadIdx.x;
    if (idx < N * K) {
        int k = idx / N;
        int n = idx - k * N;
        out[idx] = ld_flex(in, (size_t)n * K + k, bf);
    }
}

// W[N][K] row-major -> f16 k-paired full-N: u16 layout [K/2][N][2]
__global__ void k_prep_wkp(const void* __restrict__ in, u16* __restrict__ out,
                           int N, int K, const void* __restrict__ tp) {
    bool bf = probe_bf16(tp);
    int idx = blockIdx.x * 256 + threadIdx.x;
    if (idx >= N * K) return;
    int kp = idx & 1;
    int n  = (idx >> 1) % N;
    int k2 = (idx >> 1) / N;
    int k  = 2 * k2 + kp;
    float v = ld_flex(in, (size_t)n * K + k, bf);
    _Float16 hv = (_Float16)v;
    out[idx] = *(u16*)&hv;
}

// W[N][K] row-major -> bf16 [K][N]
__global__ void k_prep_wtb(const void* __restrict__ in, u16* __restrict__ out,
                           int N, int K, const void* __restrict__ tp) {
    bool bf = probe_bf16(tp);
    int idx = blockIdx.x * 256 + threadIdx.x;
    if (idx >= N * K) return;
    int n = idx % N;
    int k = idx / N;
    out[idx] = f2bf(ld_flex(in, (size_t)n * K + k, bf));
}

__global__ void k_cvt(const void* __restrict__ in, float* __restrict__ out, int n,
                      const void* __restrict__ tp) {
    bool bf = probe_bf16(tp);
    int i = blockIdx.x * 256 + threadIdx.x;
    if (i < n) out[i] = ld_flex(in, i, bf);
}

__global__ void k_cvt_add(const void* __restrict__ a, const void* __restrict__ b,
                          float* __restrict__ out, int n, const void* __restrict__ tp) {
    bool bf = probe_bf16(tp);
    int i = blockIdx.x * 256 + threadIdx.x;
    if (i < n) out[i] = ld_flex(a, i, bf) + ld_flex(b, i, bf);
}

__global__ void k_fill(float* __restrict__ out, int n, float v) {
    int i = blockIdx.x * 256 + threadIdx.x;
    if (i < n) out[i] = v;
}

// ---------------- encoder: z0 = enc(y)[:, :, 0] (only y[:, :, 0:4] matters) ----------------
__global__ __launch_bounds__(256) void k_encoder(
    const void* __restrict__ y, const void* __restrict__ tp,
    const float* __restrict__ ew0T, const float* __restrict__ rw0T, const float* __restrict__ cb0,
    const float* __restrict__ ew1T, const float* __restrict__ rw1T, const float* __restrict__ cb1,
    const float* __restrict__ ew2T, const float* __restrict__ rw2T, const float* __restrict__ cb2,
    float* __restrict__ z0f) {
    bool bf = probe_bf16(tp);
    int b = blockIdx.x;
    int o = threadIdx.x;
    __shared__ float ys[64][4];
    __shared__ float x1[3][256];
    __shared__ float x2[2][256];

    {
        int i = o >> 2, l = o & 3;
        ys[i][l] = ld_flex(y, (size_t)b * SIG_ * L_ + (size_t)i * L_ + l, bf);
    }
    __syncthreads();

    {
        float a0 = 0.f, a1 = 0.f, a2 = 0.f;
        for (int i = 0; i < 64; i++) {
            float w0 = ew0T[(i * 3 + 0) * 256 + o];
            float w1 = ew0T[(i * 3 + 1) * 256 + o];
            float w2 = ew0T[(i * 3 + 2) * 256 + o];
            float rw = rw0T[i * 256 + o];
            float v0 = ys[i][0], v1 = ys[i][1], v2 = ys[i][2], v3 = ys[i][3];
            a0 += w1 * v0 + w2 * v1 + rw * v0;
            a1 += w0 * v0 + w1 * v1 + w2 * v2 + rw * v1;
            a2 += w0 * v1 + w1 * v2 + w2 * v3 + rw * v2;
        }
        float cb = cb0[o];
        x1[0][o] = tanhf(a0 + cb);
        x1[1][o] = tanhf(a1 + cb);
        x1[2][o] = tanhf(a2 + cb);
    }
    __syncthreads();

    {
        float a0 = 0.f, a1 = 0.f;
        for (int i = 0; i < 256; i++) {
            float w0 = ew1T[(i * 3 + 0) * 256 + o];
            float w1 = ew1T[(i * 3 + 1) * 256 + o];
            float w2 = ew1T[(i * 3 + 2) * 256 + o];
            float rw = rw1T[i * 256 + o];
            float v0 = x1[0][i], v1 = x1[1][i], v2 = x1[2][i];
            a0 += w1 * v0 + w2 * v1 + rw * v0;
            a1 += w0 * v0 + w1 * v1 + w2 * v2 + rw * v1;
        }
        float cb = cb1[o];
        x2[0][o] = tanhf(a0 + cb);
        x2[1][o] = tanhf(a1 + cb);
    }
    __syncthreads();

    {
        float a0 = 0.f;
        for (int i = 0; i < 256; i++) {
            float w1 = ew2T[(i * 3 + 1) * 256 + o];
            float w2 = ew2T[(i * 3 + 2) * 256 + o];
            float rw = rw2T[i * 256 + o];
            a0 += w1 * x2[0][i] + w2 * x2[1][i] + rw * x2[0][i];
        }
        z0f[(size_t)b * 256 + o] = a0 + cb2[o];
    }
}

// ---------------- full-weight fused layer (f16 dot2), 1 row per block ----------------
// No inter-block communication. Each block streams the full f16 weight set from
// its XCD's L2 (weights are 1 MB total -> L2-resident); the first 64 k2-rows of
// fw1 (128 KB) are cached in LDS (phase-0 waves read them there).
#define TL_PLAIN 0
#define TL_RK 1
#define TL_K4 2

#define DOT4(W4, XA) \
    a.x = fdot2((W4).x, (XA), a.x); a.y = fdot2((W4).y, (XA), a.y); \
    a.z = fdot2((W4).z, (XA), a.z); a.w = fdot2((W4).w, (XA), a.w);

template <int KIN, int NOUT, bool ACT, bool ZIN, int TL, bool WC>
__device__ __forceinline__ void layer_f(
    const float* zin,                 // ZIN: f32 [KIN] input
    const unsigned* xpin,             // !ZIN: packed f16x2 [KIN/2]
    const unsigned* __restrict__ w,   // u32 [KIN/2][NOUT] (f16 k-paired)
    const float* __restrict__ bias,
    unsigned* xpo,                    // TL_PLAIN: packed out [NOUT/2]
    float* scratch,                   // LDS 2048 floats
    const unsigned* w1c,              // WC: LDS cache of first 64 k2-rows
    int tid,
    float* zbL, float* acL, float* ztL,
    bool tInit, float tcAC, float tcZT, u16* zsOut) {
    constexpr int CQ  = NOUT / 4;     // threads per phase (4 cols each)
    constexpr int NPH = 512 / CQ;     // phases over K
    constexpr int KC  = KIN / NPH;    // k per phase
    constexpr int K2C = KC / 2;       // k-pairs per thread
    const int cq = tid & (CQ - 1);
    const int ph = tid / CQ;
    const unsigned* wp = w + (size_t)(ph * K2C) * NOUT + 4 * cq;
    float4 a = {0.f, 0.f, 0.f, 0.f};
    if constexpr (ZIN) {
        const float* x0 = zin + ph * KC;
#pragma unroll 16
        for (int j = 0; j < K2C; j++) {
            uint4 w4 = *(const uint4*)(wp + (size_t)j * NOUT);
            float2 p0 = *(const float2*)(x0 + 2 * j);
            unsigned xa = pk16(p0.x, p0.y);
            DOT4(w4, xa)
        }
    } else if constexpr (WC) {
        const unsigned* q0 = xpin + ph * K2C;
        if (ph == 0) {
            // phase 0 covers k2 in [0,64) == the LDS-cached region (wave-uniform)
            const unsigned* wl = w1c + 4 * cq;
#pragma unroll 16
            for (int j = 0; j < K2C; j++) {
                uint4 w4 = *(const uint4*)(wl + (size_t)j * NOUT);
                unsigned xa = q0[j];
                DOT4(w4, xa)
            }
        } else {
#pragma unroll 16
            for (int j = 0; j < K2C; j++) {
                uint4 w4 = *(const uint4*)(wp + (size_t)j * NOUT);
                unsigned xa = q0[j];
                DOT4(w4, xa)
            }
        }
    } else {
        const unsigned* q0 = xpin + ph * K2C;
#pragma unroll 16
        for (int j = 0; j < K2C; j++) {
            uint4 w4 = *(const uint4*)(wp + (size_t)j * NOUT);
            unsigned xa = q0[j];
            DOT4(w4, xa)
        }
    }
    *(float4*)(scratch + (size_t)ph * NOUT + 4 * cq) = a;
    __syncthreads();
    if (tid < NOUT) {
        const int c = tid;
        float s = 0.f;
#pragma unroll
        for (int p = 0; p < NPH; p++) s += scratch[(size_t)p * NOUT + c];
        s += bias[c];
        if (ACT) s = fast_tanh(s);
        if constexpr (TL == TL_PLAIN) {
            float sn = __shfl_down(s, 1);
            if ((tid & 1) == 0) xpo[c >> 1] = pk16(s, sn);
        } else if constexpr (TL == TL_RK) {
            float zv = zbL[c];
            acL[c] = (tInit ? zv : acL[c]) + tcAC * s;
            ztL[c] = zv + tcZT * s;
        } else {  // TL_K4
            float zn = acL[c] + tcAC * s;
            zbL[c] = zn;
            zsOut[c] = f2bf(zn);
        }
    }
    __syncthreads();
}

// ---------------- fused ODE: 256 blocks x 512 threads, 1 row/block ----------------
__global__ __launch_bounds__(512) void k_ode_f(
    const u16* __restrict__ fw0, const float* __restrict__ fb0,
    const u16* __restrict__ fw1, const float* __restrict__ fb1,
    const u16* __restrict__ fw2, const float* __restrict__ fb2,
    const float* __restrict__ tf, const float* __restrict__ z0f,
    u16* __restrict__ zs) {
    __shared__ __align__(16) float zb[256];
    __shared__ __align__(16) float zt[256];
    __shared__ __align__(16) float ac[256];
    __shared__ __align__(16) unsigned h1p[256];   // packed f16x2
    __shared__ __align__(16) unsigned h2p[256];
    __shared__ __align__(16) float scratch[2048];
    __shared__ __align__(16) unsigned w1c[32768]; // fw1 k2<64 cache (128 KB)

    const int tid = threadIdx.x;
    const int row = blockIdx.x;
    const unsigned* fw0u = (const unsigned*)fw0;
    const unsigned* fw1u = (const unsigned*)fw1;
    const unsigned* fw2u = (const unsigned*)fw2;

    // cooperative load of the fw1 LDS cache
    for (int i = tid * 4; i < 32768; i += 2048)
        *(uint4*)&w1c[i] = *(const uint4*)&fw1u[i];

    if (tid < 256) zb[tid] = z0f[(size_t)row * 256 + tid];
    __syncthreads();
    if (tid < 256) zs[(size_t)row * 256 + tid] = f2bf(zb[tid]);

    for (int t = 0; t < T_ - 1; t++) {
        float hstep = tf[t + 1] - tf[t];
        float hh = 0.5f * hstep;
        float h3 = hstep * (1.0f / 3.0f);
        float h6 = hstep * (1.0f / 6.0f);
        u16* zo = zs + (size_t)(t + 1) * 65536 + (size_t)row * 256;

        // stage 1: k1 = rhs(zb); ac = zb + h6*k1; zt = zb + hh*k1
        layer_f<256, 512, true , true , TL_PLAIN, false>(zb, nullptr, fw0u, fb0, h1p,
            scratch, nullptr, tid, zb, ac, zt, false, 0.f, 0.f, nullptr);
        layer_f<512, 512, true , false, TL_PLAIN, true >(nullptr, h1p, fw1u, fb1, h2p,
            scratch, w1c, tid, zb, ac, zt, false, 0.f, 0.f, nullptr);
        layer_f<512, 256, false, false, TL_RK  , false>(nullptr, h2p, fw2u, fb2, nullptr,
            scratch, nullptr, tid, zb, ac, zt, true, h6, hh, nullptr);

        // stage 2: k2 = rhs(zt); ac += h3*k2; zt = zb + hh*k2
        layer_f<256, 512, true , true , TL_PLAIN, false>(zt, nullptr, fw0u, fb0, h1p,
            scratch, nullptr, tid, zb, ac, zt, false, 0.f, 0.f, nullptr);
        layer_f<512, 512, true , false, TL_PLAIN, true >(nullptr, h1p, fw1u, fb1, h2p,
            scratch, w1c, tid, zb, ac, zt, false, 0.f, 0.f, nullptr);
        layer_f<512, 256, false, false, TL_RK  , false>(nullptr, h2p, fw2u, fb2, nullptr,
            scratch, nullptr, tid, zb, ac, zt, false, h3, hh, nullptr);

        // stage 3: k3 = rhs(zt); ac += h3*k3; zt = zb + hstep*k3
        layer_f<256, 512, true , true , TL_PLAIN, false>(zt, nullptr, fw0u, fb0, h1p,
            scratch, nullptr, tid, zb, ac, zt, false, 0.f, 0.f, nullptr);
        layer_f<512, 512, true , false, TL_PLAIN, true >(nullptr, h1p, fw1u, fb1, h2p,
            scratch, w1c, tid, zb, ac, zt, false, 0.f, 0.f, nullptr);
        layer_f<512, 256, false, false, TL_RK  , false>(nullptr, h2p, fw2u, fb2, nullptr,
            scratch, nullptr, tid, zb, ac, zt, false, h3, hstep, nullptr);

        // stage 4: k4 = rhs(zt); zb = ac + h6*k4; store bf16 z_{t+1}
        layer_f<256, 512, true , true , TL_PLAIN, false>(zt, nullptr, fw0u, fb0, h1p,
            scratch, nullptr, tid, zb, ac, zt, false, 0.f, 0.f, nullptr);
        layer_f<512, 512, true , false, TL_PLAIN, true >(nullptr, h1p, fw1u, fb1, h2p,
            scratch, w1c, tid, zb, ac, zt, false, 0.f, 0.f, nullptr);
        layer_f<512, 256, false, false, TL_K4  , false>(nullptr, h2p, fw2u, fb2, nullptr,
            scratch, nullptr, tid, zb, ac, zt, false, h6, 0.f, zo);
    }
}

// ---------------- batched decode pass: zs[200*256] rows -> out ----------------
// grid 2560 = 256 b x 10 t-chunks of 20; block 512 threads
template <int K>
__device__ __forceinline__ void dec_layer512(
    const float* xin, const u16* __restrict__ wt, const float* __restrict__ bias,
    float* xout, int tid) {
    const int q = tid & 127;          // col quad (4 cols)
    const int g = tid >> 7;           // row group (5 rows)
    const u16* wp = wt + 4 * q;
    const float* xr = xin + (size_t)g * 5 * K;
    float4 a[5];
#pragma unroll
    for (int r = 0; r < 5; r++) a[r] = {0.f, 0.f, 0.f, 0.f};
#pragma unroll 4
    for (int k = 0; k < K; k++) {
        uint2 w = *(const uint2*)(wp + (size_t)k * 512);
        float w0 = __uint_as_float(w.x << 16);
        float w1 = __uint_as_float(w.x & 0xFFFF0000u);
        float w2 = __uint_as_float(w.y << 16);
        float w3 = __uint_as_float(w.y & 0xFFFF0000u);
#pragma unroll
        for (int r = 0; r < 5; r++) {
            float v = xr[r * K + k];
            a[r].x += v * w0; a[r].y += v * w1; a[r].z += v * w2; a[r].w += v * w3;
        }
    }
    float b0 = bias[4 * q + 0], b1 = bias[4 * q + 1], b2 = bias[4 * q + 2], b3 = bias[4 * q + 3];
#pragma unroll
    for (int r = 0; r < 5; r++) {
        float4 o;
        o.x = fast_tanh(a[r].x + b0);
        o.y = fast_tanh(a[r].y + b1);
        o.z = fast_tanh(a[r].z + b2);
        o.w = fast_tanh(a[r].w + b3);
        *(float4*)(xout + (size_t)(g * 5 + r) * 512 + 4 * q) = o;
    }
}

__global__ __launch_bounds__(512) void k_decode(
    const u16* __restrict__ zs,
    const u16* __restrict__ dw0b, const float* __restrict__ db0,
    const u16* __restrict__ dw1b, const float* __restrict__ db1,
    const u16* __restrict__ dw2b, const float* __restrict__ db2,
    float* __restrict__ out) {
    __shared__ __align__(16) float xb[20 * 256];    // 20 KB
    __shared__ __align__(16) float hh1[20 * 512];   // 40 KB
    __shared__ __align__(16) float hh2[20 * 512];   // 40 KB
    const int tid = threadIdx.x;
    const int b  = blockIdx.x & 255;
    const int t0 = (blockIdx.x >> 8) * 20;

    for (int i = tid; i < 20 * 256; i += 512) {
        int r = i >> 8, k = i & 255;
        xb[i] = bf2f(zs[(size_t)(t0 + r) * 65536 + (size_t)b * 256 + k]);
    }
    __syncthreads();

    dec_layer512<256>(xb, dw0b, db0, hh1, tid);
    __syncthreads();
    dec_layer512<512>(hh1, dw1b, db1, hh2, tid);
    __syncthreads();

    if (tid < 320) {
        const int q = tid & 15;       // 4 cols of 64
        const int r = tid >> 4;       // row (timestep) in [0,20)
        const u16* wp = dw2b + 4 * q;
        const float* xr = hh2 + (size_t)r * 512;
        float4 a = {0.f, 0.f, 0.f, 0.f};
#pragma unroll 4
        for (int k = 0; k < 512; k++) {
            uint2 w = *(const uint2*)(wp + (size_t)k * 64);
            float w0 = __uint_as_float(w.x << 16);
            float w1 = __uint_as_float(w.x & 0xFFFF0000u);
            float w2 = __uint_as_float(w.y << 16);
            float w3 = __uint_as_float(w.y & 0xFFFF0000u);
            float v = xr[k];
            a.x += v * w0; a.y += v * w1; a.z += v * w2; a.w += v * w3;
        }
        const int tt = t0 + r;
        out[((size_t)b * 64 + 4 * q + 0) * 200 + tt] = a.x + db2[4 * q + 0];
        out[((size_t)b * 64 + 4 * q + 1) * 200 + tt] = a.y + db2[4 * q + 1];
        out[((size_t)b * 64 + 4 * q + 2) * 200 + tt] = a.z + db2[4 * q + 2];
        out[((size_t)b * 64 + 4 * q + 3) * 200 + tt] = a.w + db2[4 * q + 3];
    }
}

// ---------------- host launch ----------------
#define GRID256(n) ((((n) + 255) / 256))

static const int DICT_SIZES[26] = {
    16777216, 200, 49152, 256, 16384, 256, 196608, 256, 65536, 256,
    196608, 256, 65536, 256, 131072, 512, 262144, 512, 131072, 256,
    131072, 512, 262144, 512, 32768, 64};
static const int ALPHA_SIZES[26] = {
    512, 512, 64, 131072, 262144, 32768, 256, 256, 256, 49152,
    196608, 196608, 512, 512, 256, 131072, 262144, 131072, 256, 256,
    256, 16384, 65536, 65536, 200, 16777216};
static const int ALPHA_MAP[26] = {
    25, 24, 9, 6, 21, 18, 10, 7, 22, 19, 11, 8, 23, 20, 15, 12, 16, 13, 17, 14,
    3, 0, 4, 1, 5, 2};

extern "C" void kernel_launch(void* const* d_in, const int* in_sizes, int n_in,
                              void* d_out, int out_size, void* d_ws, size_t ws_size,
                              hipStream_t stream) {
    float* out = (float*)d_out;   // reference output dtype is FLOAT32

    bool dict_ok = (n_in == 26), alpha_ok = (n_in == 26);
    for (int i = 0; i < 26 && i < n_in; i++) {
        if (in_sizes[i] != DICT_SIZES[i]) dict_ok = false;
        if (in_sizes[i] != ALPHA_SIZES[i]) alpha_ok = false;
    }
    const void* in[26];
    if (dict_ok) {
        for (int s = 0; s < 26; s++) in[s] = d_in[s];
    } else if (alpha_ok) {
        for (int s = 0; s < 26; s++) in[s] = d_in[ALPHA_MAP[s]];
    } else {
        k_fill<<<GRID256(out_size), 256, 0, stream>>>(out, out_size, 1000.0f);
        return;
    }
    if (ws_size < NEED_BYTES) {
        k_fill<<<GRID256(out_size), 256, 0, stream>>>(out, out_size, 500.0f);
        return;
    }

    const void* y   = in[0];
    const void* t   = in[1];
    const void* ew0 = in[2];
    const void* eb0 = in[3];
    const void* rw0 = in[4];
    const void* rb0 = in[5];
    const void* ew1 = in[6];
    const void* eb1 = in[7];
    const void* rw1 = in[8];
    const void* rb1 = in[9];
    const void* ew2 = in[10];
    const void* eb2 = in[11];
    const void* rw2 = in[12];
    const void* rb2 = in[13];
    const void* fw0 = in[14];
    const void* fb0 = in[15];
    const void* fw1 = in[16];
    const void* fb1 = in[17];
    const void* fw2 = in[18];
    const void* fb2 = in[19];
    const void* dw0 = in[20];
    const void* db0 = in[21];
    const void* dw1 = in[22];
    const void* db1 = in[23];
    const void* dw2 = in[24];
    const void* db2 = in[25];

    float* ws = (float*)d_ws;
    u16* wns = (u16*)(ws + FP32_END);

    // encoder weights stay fp32 (one-shot kernel, not on the hot path)
    k_transpose<<<GRID256(256 * 192), 256, 0, stream>>>(ew0, ws + EW0T, 256, 192, t);
    k_transpose<<<GRID256(256 * 64),  256, 0, stream>>>(rw0, ws + RW0T, 256, 64, t);
    k_transpose<<<GRID256(256 * 768), 256, 0, stream>>>(ew1, ws + EW1T, 256, 768, t);
    k_transpose<<<GRID256(256 * 256), 256, 0, stream>>>(rw1, ws + RW1T, 256, 256, t);
    k_transpose<<<GRID256(256 * 768), 256, 0, stream>>>(ew2, ws + EW2T, 256, 768, t);
    k_transpose<<<GRID256(256 * 256), 256, 0, stream>>>(rw2, ws + RW2T, 256, 256, t);

    // rhs weights -> f16 k-paired full-N [K/2][N][2]
    k_prep_wkp<<<GRID256(512 * 256), 256, 0, stream>>>(fw0, wns + FW0KP, 512, 256, t);
    k_prep_wkp<<<GRID256(512 * 512), 256, 0, stream>>>(fw1, wns + FW1KP, 512, 512, t);
    k_prep_wkp<<<GRID256(256 * 512), 256, 0, stream>>>(fw2, wns + FW2KP, 256, 512, t);
    // decoder weights -> bf16 plain-T [K][N]
    k_prep_wtb<<<GRID256(512 * 256), 256, 0, stream>>>(dw0, wns + DW0B, 512, 256, t);
    k_prep_wtb<<<GRID256(512 * 512), 256, 0, stream>>>(dw1, wns + DW1B, 512, 512, t);
    k_prep_wtb<<<GRID256(64 * 512),  256, 0, stream>>>(dw2, wns + DW2B, 64, 512, t);

    k_cvt<<<GRID256(512), 256, 0, stream>>>(fb0, ws + FB0, 512, t);
    k_cvt<<<GRID256(512), 256, 0, stream>>>(fb1, ws + FB1, 512, t);
    k_cvt<<<GRID256(256), 256, 0, stream>>>(fb2, ws + FB2, 256, t);
    k_cvt<<<GRID256(512), 256, 0, stream>>>(db0, ws + DB0, 512, t);
    k_cvt<<<GRID256(512), 256, 0, stream>>>(db1, ws + DB1, 512, t);
    k_cvt<<<GRID256(64),  256, 0, stream>>>(db2, ws + DB2, 64, t);
    k_cvt<<<GRID256(200), 256, 0, stream>>>(t,   ws + TFO, 200, t);
    k_cvt_add<<<GRID256(256), 256, 0, stream>>>(eb0, rb0, ws + CB0, 256, t);
    k_cvt_add<<<GRID256(256), 256, 0, stream>>>(eb1, rb1, ws + CB1, 256, t);
    k_cvt_add<<<GRID256(256), 256, 0, stream>>>(eb2, rb2, ws + CB2, 256, t);

    k_encoder<<<B_, 256, 0, stream>>>(y, t,
        ws + EW0T, ws + RW0T, ws + CB0,
        ws + EW1T, ws + RW1T, ws + CB1,
        ws + EW2T, ws + RW2T, ws + CB2,
        ws + Z0F);

    k_ode_f<<<B_, 512, 0, stream>>>(
        wns + FW0KP, ws + FB0, wns + FW1KP, ws + FB1, wns + FW2KP, ws + FB2,
        ws + TFO, ws + Z0F, wns + ZS);

    k_decode<<<2560, 512, 0, stream>>>(
        wns + ZS, wns + DW0B, ws + DB0, wns + DW1B, ws + DB1, wns + DW2B, ws + DB2, out);
}